// Round 4
// baseline (98.096 us; speedup 1.0000x reference)
//
#include <hip/hip_runtime.h>
#include <hip/hip_bf16.h>
#include <cmath>

// Problem constants (fixed by reference)
#define NPTS  4096
#define HW    16384       // 128*128
#define WIDTH 128
#define NVIEW 4
#define KTOP  5
#define NBIN  128
#define CAP   2048        // LDS candidate capacity (expected ~128; 4096*P(bin in 4/128) -> ~170 sigma margin)

struct AllViews {
    // per view: row-major 3x3 (axis_i dotted with p) then T (tx,ty,tz)
    float m[NVIEW][12];
};

// One block per (view, row-pair). Fully fused: transform+filter+sigmoid+top-K+composite.
__global__ __launch_bounds__(256)
void raster_fused(const float* __restrict__ pcd,
                  const float* __restrict__ displace,
                  const float* __restrict__ init_colors,
                  float* __restrict__ out,
                  float* __restrict__ out_colors,
                  AllViews av) {
    __shared__ float4 buf[CAP + 4];
    __shared__ int cnt;

    const int v   = blockIdx.x >> 6;
    const int r   = blockIdx.x & 63;        // row-pair within view
    const int y0  = r << 1;
    const int tid = threadIdx.x;
    const float* M = av.m[v];

    if (tid == 0) cnt = 0;

    // colors_ output tail: view-0 blocks each cover 64 points (64 blocks * 64 = 4096)
    if (v == 0 && tid < 64) {
        int n = (r << 6) + tid;
        out_colors[n] = 1.0f / (1.0f + expf(-(init_colors[n] + displace[n])));
    }
    __syncthreads();

    // Scan all 4096 points of this view: transform, y-bin filter, append survivors.
    #pragma unroll
    for (int t = 0; t < 16; ++t) {
        int n = tid + (t << 8);
        float p0 = pcd[3 * n + 0];
        float p1 = pcd[3 * n + 1];
        float p2 = pcd[3 * n + 2];
        float py  = fmaf(p0, M[3], fmaf(p1, M[4], fmaf(p2, M[5], M[10])));
        int b = (int)floorf((1.0f - py) * 64.0f);
        b = min(max(b, 0), NBIN - 1);
        if ((b >= y0 - 1) & (b <= y0 + 2)) {
            float px  = fmaf(p0, M[0], fmaf(p1, M[1], fmaf(p2, M[2], M[9])));
            float pvz = fmaf(p0, M[6], fmaf(p1, M[7], fmaf(p2, M[8], M[11])));
            float pz  = (pvz - 0.01f) * (1.0f / 99.99f);
            float s   = 1.0f / (1.0f + expf(-(init_colors[n] + displace[n])));
            int pos = atomicAdd(&cnt, 1);
            if (pos < CAP) buf[pos] = make_float4(px, py, pz, s);
        }
    }
    __syncthreads();

    int m = min(cnt, CAP);
    int mpad = (m + 3) & ~3;
    if (tid < mpad - m) buf[m + tid] = make_float4(1.0e9f, 1.0e9f, -1.0f, 0.0f); // pz<0 -> rejected
    __syncthreads();

    const int yi = y0 + (tid >> 7);
    const int xi = tid & (WIDTH - 1);
    const float xf = 1.0f - (2.0f * (float)xi + 1.0f) * (1.0f / 128.0f);
    const float yf = 1.0f - (2.0f * (float)yi + 1.0f) * (1.0f / 128.0f);

    const float R2f   = (float)(0.02 * 0.02);
    const float invR2 = 1.0f / R2f;

    float zs[KTOP], as_[KTOP], cs[KTOP];
    #pragma unroll
    for (int k = 0; k < KTOP; ++k) { zs[k] = 3.0e38f; as_[k] = 0.0f; cs[k] = 0.0f; }

    #define PROC(pt)                                                        \
    {                                                                       \
        float dx = (pt).x - xf;                                             \
        float dy = (pt).y - yf;                                             \
        float d2 = fmaf(dx, dx, dy * dy);                                   \
        if ((d2 < R2f) & ((pt).z > 0.0f) & ((pt).z < zs[KTOP - 1])) {       \
            float nz = (pt).z;                                              \
            float na = 1.0f - d2 * invR2;                                   \
            float nc = (pt).w;                                              \
            _Pragma("unroll")                                               \
            for (int k = 0; k < KTOP; ++k) {                                \
                bool sw = nz < zs[k];                                       \
                float oz = zs[k], oa = as_[k], oc = cs[k];                  \
                zs[k]  = sw ? nz : oz;                                      \
                as_[k] = sw ? na : oa;                                      \
                cs[k]  = sw ? nc : oc;                                      \
                nz = sw ? oz : nz;                                          \
                na = sw ? oa : na;                                          \
                nc = sw ? oc : nc;                                          \
            }                                                               \
        }                                                                   \
    }

    for (int j = 0; j < mpad; j += 4) {
        float4 c0 = buf[j + 0];
        float4 c1 = buf[j + 1];
        float4 c2 = buf[j + 2];
        float4 c3 = buf[j + 3];
        PROC(c0); PROC(c1); PROC(c2); PROC(c3);
    }
    #undef PROC

    float t = 1.0f, pix = 0.0f;
    #pragma unroll
    for (int k = 0; k < KTOP; ++k) {
        pix += as_[k] * t * cs[k];
        t *= (1.0f - as_[k]);
    }

    const int p = (blockIdx.x << 8) + tid;   // v*HW + y0*128 + tid (contiguous)
    float* o = out + 3 * (size_t)p;
    o[0] = pix; o[1] = pix; o[2] = pix;
}

static void compute_views(AllViews* av) {
    const double dist = 1.5;
    const double elev = 15.0 * M_PI / 180.0;
    const double az_deg[NVIEW] = {0.0, 90.0, 180.0, 270.0};
    for (int v = 0; v < NVIEW; ++v) {
        double az = az_deg[v] * M_PI / 180.0;
        double C[3] = { dist * cos(elev) * sin(az),
                        dist * sin(elev),
                        dist * cos(elev) * cos(az) };
        double nC = sqrt(C[0]*C[0] + C[1]*C[1] + C[2]*C[2]);
        double z[3] = { -C[0]/nC, -C[1]/nC, -C[2]/nC };
        double up[3] = { 0.0, 1.0, 0.0 };
        double x[3] = { up[1]*z[2] - up[2]*z[1],
                        up[2]*z[0] - up[0]*z[2],
                        up[0]*z[1] - up[1]*z[0] };
        double nx = sqrt(x[0]*x[0] + x[1]*x[1] + x[2]*x[2]);
        x[0] /= nx; x[1] /= nx; x[2] /= nx;
        double y[3] = { z[1]*x[2] - z[2]*x[1],
                        z[2]*x[0] - z[0]*x[2],
                        z[0]*x[1] - z[1]*x[0] };
        double* axes[3] = { x, y, z };
        for (int i = 0; i < 3; ++i) {
            av->m[v][3*i + 0] = (float)axes[i][0];
            av->m[v][3*i + 1] = (float)axes[i][1];
            av->m[v][3*i + 2] = (float)axes[i][2];
            av->m[v][9 + i] = (float)(-(axes[i][0]*C[0] + axes[i][1]*C[1] + axes[i][2]*C[2]));
        }
    }
}

extern "C" void kernel_launch(void* const* d_in, const int* in_sizes, int n_in,
                              void* d_out, int out_size, void* d_ws, size_t ws_size,
                              hipStream_t stream) {
    const float* pcd         = (const float*)d_in[0];
    const float* displace    = (const float*)d_in[1];
    const float* init_colors = (const float*)d_in[2];
    float* out = (float*)d_out;
    float* out_colors = out + (size_t)NVIEW * HW * 3;

    AllViews av;
    compute_views(&av);

    raster_fused<<<NVIEW * 64, 256, 0, stream>>>(pcd, displace, init_colors,
                                                 out, out_colors, av);
}